// Round 10
// baseline (523.591 us; speedup 1.0000x reference)
//
#include <hip/hip_runtime.h>
#include <math.h>

#define N_USERS 40000
#define N_ITEMS 20000
#define NNODES  60000          // N_USERS + N_ITEMS; also the zero-pad row index
#define D       128
#define N_EDGES 320000
#define EPS_    1e-7f
#define BATCH   4096
#define STRIDE  64             // ELL row capacity (max degree ~45 for Poisson(16))
#define ZSCALE  256.0f         // fp8 storage scale; folded out in bpr
#define REPS    16             // MEASUREMENT: in-kernel idempotent repeat count
#define BPR_BLOCKS (BATCH / 8)             // 512: 4 waves x 2 elements each
#define FILL_GRPS  320                     // blocks per bucket
#define FILL_BLOCKS (8 * FILL_GRPS)        // 2560
#define INIT_BLOCKS (((NNODES + 1) * 16 + 255) / 256)  // 3751 (16 thr/row, +pad row)
#define FULL_BLOCKS (NNODES * 8 / 256)     // 1875 (8 threads per row)

// MEASUREMENT ROUND (R10). R9 pinned q(spmm dispatch) = 13.5us; the other
// ~135us of the 162.6 baseline is unattributed across fill/init/bpr and my
// bottom-up models are 3-4x off. This round repeats init/spmm/bpr bodies
// x16 IN-KERNEL (idempotent; bpr commits results only on the last rep) so
// each phase's dispatch exceeds the ~43us poison-fill cutoff and shows up
// in the rocprof top-5 WITH counters. The `zero` runtime arg (host passes
// 0) perturbs indices per-rep so the compiler cannot hoist/CSE the loads.
// fill is not idempotent (atomics) -> stays x1, attributed by subtraction.

typedef float vf2 __attribute__((ext_vector_type(2)));

// unpack 16 fp8 (e4m3) from uint4, accumulate into 8 packed-f32 pairs.
__device__ __forceinline__ void add_fp8x16v(vf2* a, uint4 t) {
    a[0] += __builtin_amdgcn_cvt_pk_f32_fp8(t.x, false);
    a[1] += __builtin_amdgcn_cvt_pk_f32_fp8(t.x, true);
    a[2] += __builtin_amdgcn_cvt_pk_f32_fp8(t.y, false);
    a[3] += __builtin_amdgcn_cvt_pk_f32_fp8(t.y, true);
    a[4] += __builtin_amdgcn_cvt_pk_f32_fp8(t.z, false);
    a[5] += __builtin_amdgcn_cvt_pk_f32_fp8(t.z, true);
    a[6] += __builtin_amdgcn_cvt_pk_f32_fp8(t.w, false);
    a[7] += __builtin_amdgcn_cvt_pk_f32_fp8(t.w, true);
}

// scale + clamp + pack 8 vf2 (16 f32) -> 16 fp8 (e4m3) in uint4
__device__ __forceinline__ uint4 pack_fp8x16v(const vf2* a, float w) {
    float v[16];
    #pragma unroll
    for (int k = 0; k < 8; ++k) {
        v[2 * k]     = fminf(fmaxf(w * a[k].x, -448.0f), 448.0f);
        v[2 * k + 1] = fminf(fmaxf(w * a[k].y, -448.0f), 448.0f);
    }
    int w0 = __builtin_amdgcn_cvt_pk_fp8_f32(v[0],  v[1],  0,  false);
    w0     = __builtin_amdgcn_cvt_pk_fp8_f32(v[2],  v[3],  w0, true);
    int w1 = __builtin_amdgcn_cvt_pk_fp8_f32(v[4],  v[5],  0,  false);
    w1     = __builtin_amdgcn_cvt_pk_fp8_f32(v[6],  v[7],  w1, true);
    int w2 = __builtin_amdgcn_cvt_pk_fp8_f32(v[8],  v[9],  0,  false);
    w2     = __builtin_amdgcn_cvt_pk_fp8_f32(v[10], v[11], w2, true);
    int w3 = __builtin_amdgcn_cvt_pk_fp8_f32(v[12], v[13], 0,  false);
    w3     = __builtin_amdgcn_cvt_pk_fp8_f32(v[14], v[15], w3, true);
    uint4 o; o.x = (unsigned)w0; o.y = (unsigned)w1;
    o.z = (unsigned)w2; o.w = (unsigned)w3;
    return o;
}

// gather 8 padded edges (2 int4 col loads, 8 uint4 gathers all in flight)
__device__ __forceinline__ void gather8(const int4* __restrict__ rcv, int t,
                                        const uint4* __restrict__ z, int sub,
                                        vf2* a) {
    int4 ca = rcv[2 * t], cb = rcv[2 * t + 1];
    uint4 t0 = z[(ca.x << 3) + sub];
    uint4 t1 = z[(ca.y << 3) + sub];
    uint4 t2 = z[(ca.z << 3) + sub];
    uint4 t3 = z[(ca.w << 3) + sub];
    uint4 t4 = z[(cb.x << 3) + sub];
    uint4 t5 = z[(cb.y << 3) + sub];
    uint4 t6 = z[(cb.z << 3) + sub];
    uint4 t7 = z[(cb.w << 3) + sub];
    add_fp8x16v(a, t0); add_fp8x16v(a, t1);
    add_fp8x16v(a, t2); add_fp8x16v(a, t3);
    add_fp8x16v(a, t4); add_fp8x16v(a, t5);
    add_fp8x16v(a, t6); add_fp8x16v(a, t7);
}

// ---- bucketed ELL fill (int4-vectorized); fillc ends holding the degree --
// users: bucket = u/10000 (0..3); items: bucket = 4 + i/5000.
// XCD-local scatter writes via blockIdx&7 round-robin (R11: -30us vs naive).
// NOT repeated (atomics are not idempotent) — attributed by subtraction.
__global__ void fill_ell(const int4* __restrict__ au4, const int4* __restrict__ ai4,
                         int* __restrict__ fillc, int* __restrict__ colell) {
    const int bucket = blockIdx.x & 7;
    const int grp    = blockIdx.x >> 3;          // 0..FILL_GRPS-1
    const int NE4    = N_EDGES / 4;
    for (int i = grp * 256 + threadIdx.x; i < NE4; i += FILL_GRPS * 256) {
        int4 us = au4[i];
        int4 is = ai4[i];
        int ua[4] = { us.x, us.y, us.z, us.w };
        int ia[4] = { is.x, is.y, is.z, is.w };
        #pragma unroll
        for (int k = 0; k < 4; ++k) {
            int u    = ua[k];
            int iraw = ia[k];
            int it   = N_USERS + iraw;
            if (u / 10000 == bucket) {
                int p = atomicAdd(&fillc[u], 1);
                if (p < STRIDE) colell[(u << 6) + p] = it;
            }
            if (4 + iraw / 5000 == bucket) {
                int p = atomicAdd(&fillc[it], 1);
                if (p < STRIDE) colell[(it << 6) + p] = u;
            }
        }
    }
}

// ---- z0 init + colell 8-padding + zero-row init, x16 idempotent repeat ---
__global__ void init_z(const int* __restrict__ fillc,
                       const float4* __restrict__ ue, const float4* __restrict__ ie,
                       uint2* __restrict__ z0, uint2* __restrict__ z1,
                       uint2* __restrict__ z2, int* __restrict__ colell,
                       int zero) {
    int i0 = blockIdx.x * 256 + threadIdx.x;
    if (i0 >= (NNODES + 1) * 16) return;
    for (int rep = 0; rep < REPS; ++rep) {
        int i   = i0 + zero * rep;           // == i0 at runtime; opaque to comp.
        int row = i >> 4;
        int sub = i & 15;
        if (row == NNODES) {                 // zero-pad row in all three buffers
            uint2 zz = make_uint2(0u, 0u);
            z0[i] = zz; z1[i] = zz; z2[i] = zz;
            continue;
        }
        int e = fillc[row];
        if (sub == 0) {                      // pad colell row to a multiple of 8
            int ep = (e + 7) & ~7;
            for (int k = e; k < ep; ++k) colell[(row << 6) + k] = NNODES;
        }
        float w = rsqrtf((float)e + EPS_) * ZSCALE;
        float4 e0, e1;
        if (row < N_USERS) {
            int b4 = row * 32 + sub * 2;     // 32 float4 per row
            e0 = ue[b4]; e1 = ue[b4 + 1];
        } else {
            int b4 = (row - N_USERS) * 32 + sub * 2;
            e0 = ie[b4]; e1 = ie[b4 + 1];
        }
        float v[8] = { e0.x * w, e0.y * w, e0.z * w, e0.w * w,
                       e1.x * w, e1.y * w, e1.z * w, e1.w * w };
        float c[8];
        #pragma unroll
        for (int k = 0; k < 8; ++k) c[k] = fminf(fmaxf(v[k], -448.0f), 448.0f);
        int lo = __builtin_amdgcn_cvt_pk_fp8_f32(c[0], c[1], 0,  false);
        lo     = __builtin_amdgcn_cvt_pk_fp8_f32(c[2], c[3], lo, true);
        int hi = __builtin_amdgcn_cvt_pk_fp8_f32(c[4], c[5], 0,  false);
        hi     = __builtin_amdgcn_cvt_pk_fp8_f32(c[6], c[7], hi, true);
        z0[i] = make_uint2((unsigned)lo, (unsigned)hi);
    }
}

// ---- SpMM, 8-lane subgroup rows, x16 idempotent repeat -------------------
__device__ __forceinline__ void spmm_body(const int* __restrict__ cnt,
                                          const int* __restrict__ colell,
                                          const uint4* __restrict__ z,
                                          uint4* __restrict__ znxt, int zero) {
    int tid = blockIdx.x * 256 + threadIdx.x;
    int sub = threadIdx.x & 7;
    for (int rep = 0; rep < REPS; ++rep) {
        int row = (tid >> 3) + zero * rep;   // == tid>>3 at runtime
        int e = cnt[row];
        const int4* rcv = (const int4*)(colell + (row << 6));
        vf2 a[8];
        #pragma unroll
        for (int k = 0; k < 8; ++k) a[k] = (vf2)(0.0f);
        int nchunks = (e + 7) >> 3;
        for (int t = 0; t < nchunks; ++t) gather8(rcv, t, z, sub, a);
        float w = 1.0f / ((float)e + EPS_);  // dinv^2
        znxt[(row << 3) + sub] = pack_fp8x16v(a, w);
    }
}

__global__ void spmm_L1(const int* __restrict__ cnt, const int* __restrict__ colell,
                        const uint4* __restrict__ z, uint4* __restrict__ znxt,
                        int zero) {
    spmm_body(cnt, colell, z, znxt, zero);
}
__global__ void spmm_L2(const int* __restrict__ cnt, const int* __restrict__ colell,
                        const uint4* __restrict__ z, uint4* __restrict__ znxt,
                        int zero) {
    spmm_body(cnt, colell, z, znxt, zero);
}

// ---- fused BPR loss, x16 repeat; commits s/lacc/done only on last rep ----
__global__ void bpr_loss(const float4* __restrict__ ue, const float4* __restrict__ ie,
                         const uint4* __restrict__ z1, const uint4* __restrict__ z2,
                         const int* __restrict__ cnt, const int* __restrict__ colell,
                         const int* __restrict__ user, const int* __restrict__ pos,
                         const int* __restrict__ neg,
                         float* __restrict__ lacc, int* __restrict__ done,
                         float* __restrict__ out, int zero) {
    __shared__ float s[8];
    int wave = (blockIdx.x * 256 + threadIdx.x) >> 6;   // global wave id
    int lane = threadIdx.x & 63;
    int sg   = lane >> 3;          // 0..7
    int sub  = lane & 7;
    int half = sg >> 2;            // 0 = elem A, 1 = elem B
    int sgl  = sg & 3;             // 0=u 1=p 2=n 3=idle
    for (int rep = 0; rep < REPS; ++rep) {
        int el = wave * 2 + half + zero * rep;   // == wave*2+half at runtime
        int u = user[el];
        int p = N_USERS + pos[el] - 1;  // 1-indexed items
        int n = N_USERS + neg[el] - 1;
        int node = (sgl == 1) ? p : (sgl == 2) ? n : u;
        float cnode = 0.0f;
        vf2 vals[8];
        #pragma unroll
        for (int k = 0; k < 8; ++k) vals[k] = (vf2)(0.0f);
        if (sgl < 3) {
            int e = cnt[node];
            cnode = (float)e;
            // layer-0 exact from f32 embeddings: 4 float4 per lane
            const float4* eb = (node < N_USERS) ? ue : ie;
            int b4 = ((node < N_USERS) ? node : node - N_USERS) * 32 + sub * 4;
            float4 e0 = eb[b4], e1 = eb[b4 + 1], e2 = eb[b4 + 2], e3 = eb[b4 + 3];
            float w0 = rsqrtf(cnode + EPS_) * ZSCALE;
            vals[0] = (vf2){w0 * e0.x, w0 * e0.y}; vals[1] = (vf2){w0 * e0.z, w0 * e0.w};
            vals[2] = (vf2){w0 * e1.x, w0 * e1.y}; vals[3] = (vf2){w0 * e1.z, w0 * e1.w};
            vals[4] = (vf2){w0 * e2.x, w0 * e2.y}; vals[5] = (vf2){w0 * e2.z, w0 * e2.w};
            vals[6] = (vf2){w0 * e3.x, w0 * e3.y}; vals[7] = (vf2){w0 * e3.z, w0 * e3.w};
            int o = (node << 3) + sub;
            add_fp8x16v(vals, z1[o]);
            add_fp8x16v(vals, z2[o]);
            // inline layer-3 gather from z2 (f32), 8-edge padded chunks
            const int4* rcv = (const int4*)(colell + (node << 6));
            vf2 a[8];
            #pragma unroll
            for (int k = 0; k < 8; ++k) a[k] = (vf2)(0.0f);
            int nchunks = (e + 7) >> 3;
            for (int t = 0; t < nchunks; ++t) gather8(rcv, t, z2, sub, a);
            float w2 = 1.0f / (cnode + EPS_);   // dinv^2
            #pragma unroll
            for (int k = 0; k < 8; ++k) vals[k] += w2 * a[k];
        }
        // pull the u-subgroup (sg0 / sg4) values into all subgroups of the half
        int usrc = sub | (lane & 32);
        float dotp = 0.0f;
        #pragma unroll
        for (int k = 0; k < 8; ++k) {
            dotp += __shfl(vals[k].x, usrc) * vals[k].x;
            dotp += __shfl(vals[k].y, usrc) * vals[k].y;
        }
        dotp += __shfl_down(dotp, 4, 8);
        dotp += __shfl_down(dotp, 2, 8);
        dotp += __shfl_down(dotp, 1, 8);
        // subgroup heads now hold: lane (lane&32)+8 -> u.p, +16 -> u.n
        float sp = __shfl(dotp, (lane & 32) + 8);
        float sn = __shfl(dotp, (lane & 32) + 16);
        float cu = __shfl(cnode, (lane & 32) + 0);
        float cp = __shfl(cnode, (lane & 32) + 8);
        float cn = __shfl(cnode, (lane & 32) + 16);
        if ((lane & 31) == 0 && rep == REPS - 1) {
            float du = rsqrtf(cu + EPS_), dp = rsqrtf(cp + EPS_), dn = rsqrtf(cn + EPS_);
            const float inv = 1.0f / (16.0f * ZSCALE * ZSCALE);
            float diff = (sp / (du * dp) - sn / (du * dn)) * inv;
            // log_sigmoid(x) = min(x,0) - log1p(exp(-|x|))
            s[(threadIdx.x >> 6) * 2 + half] =
                fminf(diff, 0.0f) - log1pf(expf(-fabsf(diff)));
        }
    }
    __syncthreads();
    if (threadIdx.x == 0) {
        float t = s[0] + s[1] + s[2] + s[3] + s[4] + s[5] + s[6] + s[7];
        atomicAdd(lacc, t);
        __threadfence();
        int prev = atomicAdd(done, 1);
        if (prev == BPR_BLOCKS - 1) {
            float total = atomicAdd(lacc, 0.0f);   // coherent read
            out[0] = -total * (1.0f / (float)BATCH);
        }
    }
}

extern "C" void kernel_launch(void* const* d_in, const int* in_sizes, int n_in,
                              void* d_out, int out_size, void* d_ws, size_t ws_size,
                              hipStream_t stream) {
    const float* ue  = (const float*)d_in[0];
    const float* ie  = (const float*)d_in[1];
    const int*   au  = (const int*)d_in[2];
    const int*   ai  = (const int*)d_in[3];
    const int*   usr = (const int*)d_in[4];
    const int*   pos = (const int*)d_in[5];
    const int*   neg = (const int*)d_in[6];
    float*       out = (float*)d_out;

    const size_t ZQ4 = (size_t)(NNODES + 1) * 8;  // uint4 per z buffer (+zero row)

    // ws layout (16B-aligned chunks):
    // z0 | z1 | z2 (fp8, NNODES+1 rows) | [fillc | lacc | done | pad] | colell
    uint4* z0     = (uint4*)d_ws;
    uint4* z1     = z0 + ZQ4;
    uint4* z2     = z1 + ZQ4;
    int*   fillc  = (int*)(z2 + ZQ4);
    float* lacc   = (float*)(fillc + NNODES);
    int*   done   = (int*)(lacc + 1);
    int*   colell = (int*)(lacc + 4);             // NNODES * STRIDE ints

    // fillc + lacc + done zeroed in one shot
    hipMemsetAsync(fillc, 0, (NNODES + 4) * sizeof(int), stream);

    fill_ell<<<FILL_BLOCKS, 256, 0, stream>>>((const int4*)au, (const int4*)ai,
                                              fillc, colell);
    init_z<<<INIT_BLOCKS, 256, 0, stream>>>(fillc, (const float4*)ue,
                                            (const float4*)ie, (uint2*)z0,
                                            (uint2*)z1, (uint2*)z2, colell, 0);

    spmm_L1<<<FULL_BLOCKS, 256, 0, stream>>>(fillc, colell, z0, z1, 0);
    spmm_L2<<<FULL_BLOCKS, 256, 0, stream>>>(fillc, colell, z1, z2, 0);

    bpr_loss<<<BPR_BLOCKS, 256, 0, stream>>>((const float4*)ue, (const float4*)ie,
                                             z1, z2, fillc, colell,
                                             usr, pos, neg, lacc, done, out, 0);
}

// Round 11
// 225.850 us; speedup vs baseline: 2.3183x; 2.3183x over previous
//
#include <hip/hip_runtime.h>
#include <math.h>

#define N_USERS 40000
#define N_ITEMS 20000
#define NNODES  60000          // N_USERS + N_ITEMS; also the zero-pad row index
#define D       128
#define N_EDGES 320000
#define EPS_    1e-7f
#define BATCH   4096
#define STRIDE  64             // ELL row capacity (max degree ~45 for Poisson(16))
#define ZSCALE  256.0f         // fp8 storage scale; folded out in bpr
#define BPR_BLOCKS (BATCH / 8)             // 512: 4 waves x 2 elements each
#define FILL_GRPS  320                     // blocks per bucket
#define FILL_BLOCKS (8 * FILL_GRPS)        // 2560
#define INIT_BLOCKS (((NNODES + 1) * 16 + 255) / 256)  // 3751 (16 thr/row, +pad row)
#define FULL_BLOCKS (NNODES * 8 / 256)     // 1875 (8 threads per row)

// PHASE BUDGET (measured R9/R10): spmm = 9.35us warm, VALUBusy 68% (VALU-
// bound on fp8 unpack), occupancy 43%; init < 2.7us warm; bpr < 2.7us warm;
// same-kernel dispatch boundary ~4.2us. That accounts for ~60us of the
// 162.6 baseline; the ONLY unmeasured phase is fill_ell (~100us residual
// candidate). MEASUREMENT ROUND (R11): dispatch fill 3x — replicas 1+2 on
// zeroed scratch counters (fillc2/fillc3, byte-identical behavior, scatter
// to scratch colell2), then the real fill. dur = 162.6 + 2*(F_warm + ~4).
// F>43us => fill shows in top-5 with counters. Decision pre-committed:
// big F -> redesign fill; small F -> boundaries/cold-start are the target.

typedef float vf2 __attribute__((ext_vector_type(2)));

// unpack 16 fp8 (e4m3) from uint4, accumulate into 8 packed-f32 pairs.
__device__ __forceinline__ void add_fp8x16v(vf2* a, uint4 t) {
    a[0] += __builtin_amdgcn_cvt_pk_f32_fp8(t.x, false);
    a[1] += __builtin_amdgcn_cvt_pk_f32_fp8(t.x, true);
    a[2] += __builtin_amdgcn_cvt_pk_f32_fp8(t.y, false);
    a[3] += __builtin_amdgcn_cvt_pk_f32_fp8(t.y, true);
    a[4] += __builtin_amdgcn_cvt_pk_f32_fp8(t.z, false);
    a[5] += __builtin_amdgcn_cvt_pk_f32_fp8(t.z, true);
    a[6] += __builtin_amdgcn_cvt_pk_f32_fp8(t.w, false);
    a[7] += __builtin_amdgcn_cvt_pk_f32_fp8(t.w, true);
}

// scale + clamp + pack 8 vf2 (16 f32) -> 16 fp8 (e4m3) in uint4
__device__ __forceinline__ uint4 pack_fp8x16v(const vf2* a, float w) {
    float v[16];
    #pragma unroll
    for (int k = 0; k < 8; ++k) {
        v[2 * k]     = fminf(fmaxf(w * a[k].x, -448.0f), 448.0f);
        v[2 * k + 1] = fminf(fmaxf(w * a[k].y, -448.0f), 448.0f);
    }
    int w0 = __builtin_amdgcn_cvt_pk_fp8_f32(v[0],  v[1],  0,  false);
    w0     = __builtin_amdgcn_cvt_pk_fp8_f32(v[2],  v[3],  w0, true);
    int w1 = __builtin_amdgcn_cvt_pk_fp8_f32(v[4],  v[5],  0,  false);
    w1     = __builtin_amdgcn_cvt_pk_fp8_f32(v[6],  v[7],  w1, true);
    int w2 = __builtin_amdgcn_cvt_pk_fp8_f32(v[8],  v[9],  0,  false);
    w2     = __builtin_amdgcn_cvt_pk_fp8_f32(v[10], v[11], w2, true);
    int w3 = __builtin_amdgcn_cvt_pk_fp8_f32(v[12], v[13], 0,  false);
    w3     = __builtin_amdgcn_cvt_pk_fp8_f32(v[14], v[15], w3, true);
    uint4 o; o.x = (unsigned)w0; o.y = (unsigned)w1;
    o.z = (unsigned)w2; o.w = (unsigned)w3;
    return o;
}

// gather 8 padded edges (2 int4 col loads, 8 uint4 gathers all in flight)
__device__ __forceinline__ void gather8(const int4* __restrict__ rcv, int t,
                                        const uint4* __restrict__ z, int sub,
                                        vf2* a) {
    int4 ca = rcv[2 * t], cb = rcv[2 * t + 1];
    uint4 t0 = z[(ca.x << 3) + sub];
    uint4 t1 = z[(ca.y << 3) + sub];
    uint4 t2 = z[(ca.z << 3) + sub];
    uint4 t3 = z[(ca.w << 3) + sub];
    uint4 t4 = z[(cb.x << 3) + sub];
    uint4 t5 = z[(cb.y << 3) + sub];
    uint4 t6 = z[(cb.z << 3) + sub];
    uint4 t7 = z[(cb.w << 3) + sub];
    add_fp8x16v(a, t0); add_fp8x16v(a, t1);
    add_fp8x16v(a, t2); add_fp8x16v(a, t3);
    add_fp8x16v(a, t4); add_fp8x16v(a, t5);
    add_fp8x16v(a, t6); add_fp8x16v(a, t7);
}

// ---- bucketed ELL fill (int4-vectorized); fillc ends holding the degree --
// users: bucket = u/10000 (0..3); items: bucket = 4 + i/5000.
// XCD-local scatter writes via blockIdx&7 round-robin (R11: -30us vs naive).
__global__ void fill_ell(const int4* __restrict__ au4, const int4* __restrict__ ai4,
                         int* __restrict__ fillc, int* __restrict__ colell) {
    const int bucket = blockIdx.x & 7;
    const int grp    = blockIdx.x >> 3;          // 0..FILL_GRPS-1
    const int NE4    = N_EDGES / 4;
    for (int i = grp * 256 + threadIdx.x; i < NE4; i += FILL_GRPS * 256) {
        int4 us = au4[i];
        int4 is = ai4[i];
        int ua[4] = { us.x, us.y, us.z, us.w };
        int ia[4] = { is.x, is.y, is.z, is.w };
        #pragma unroll
        for (int k = 0; k < 4; ++k) {
            int u    = ua[k];
            int iraw = ia[k];
            int it   = N_USERS + iraw;
            if (u / 10000 == bucket) {
                int p = atomicAdd(&fillc[u], 1);
                if (p < STRIDE) colell[(u << 6) + p] = it;
            }
            if (4 + iraw / 5000 == bucket) {
                int p = atomicAdd(&fillc[it], 1);
                if (p < STRIDE) colell[(it << 6) + p] = u;
            }
        }
    }
}

// ---- z0 init + colell 8-padding + zero-row init --------------------------
// 16 threads per row. Row NNODES is the shared zero row of z0/z1/z2.
__global__ void init_z(const int* __restrict__ fillc,
                       const float4* __restrict__ ue, const float4* __restrict__ ie,
                       uint2* __restrict__ z0, uint2* __restrict__ z1,
                       uint2* __restrict__ z2, int* __restrict__ colell) {
    int i   = blockIdx.x * 256 + threadIdx.x;
    if (i >= (NNODES + 1) * 16) return;
    int row = i >> 4;
    int sub = i & 15;
    if (row == NNODES) {                 // zero-pad row in all three buffers
        uint2 zz = make_uint2(0u, 0u);
        z0[i] = zz; z1[i] = zz; z2[i] = zz;
        return;
    }
    int e = fillc[row];
    if (sub == 0) {                      // pad colell row to a multiple of 8
        int ep = (e + 7) & ~7;
        for (int k = e; k < ep; ++k) colell[(row << 6) + k] = NNODES;
    }
    float w = rsqrtf((float)e + EPS_) * ZSCALE;
    float4 e0, e1;
    if (row < N_USERS) {
        int b4 = row * 32 + sub * 2;     // 32 float4 per row
        e0 = ue[b4]; e1 = ue[b4 + 1];
    } else {
        int b4 = (row - N_USERS) * 32 + sub * 2;
        e0 = ie[b4]; e1 = ie[b4 + 1];
    }
    float v[8] = { e0.x * w, e0.y * w, e0.z * w, e0.w * w,
                   e1.x * w, e1.y * w, e1.z * w, e1.w * w };
    float c[8];
    #pragma unroll
    for (int k = 0; k < 8; ++k) c[k] = fminf(fmaxf(v[k], -448.0f), 448.0f);
    int lo = __builtin_amdgcn_cvt_pk_fp8_f32(c[0], c[1], 0,  false);
    lo     = __builtin_amdgcn_cvt_pk_fp8_f32(c[2], c[3], lo, true);
    int hi = __builtin_amdgcn_cvt_pk_fp8_f32(c[4], c[5], 0,  false);
    hi     = __builtin_amdgcn_cvt_pk_fp8_f32(c[6], c[7], hi, true);
    z0[i] = make_uint2((unsigned)lo, (unsigned)hi);
}

// ---- SpMM, 8-lane subgroup rows, 8-edge padded chunks (mixed rows) -------
__device__ __forceinline__ void spmm_body(const int* __restrict__ cnt,
                                          const int* __restrict__ colell,
                                          const uint4* __restrict__ z,
                                          uint4* __restrict__ znxt) {
    int tid = blockIdx.x * 256 + threadIdx.x;
    int row = tid >> 3;               // 32 rows per 256-thread block
    int sub = threadIdx.x & 7;
    int e = cnt[row];
    const int4* rcv = (const int4*)(colell + (row << 6));
    vf2 a[8];
    #pragma unroll
    for (int k = 0; k < 8; ++k) a[k] = (vf2)(0.0f);
    int nchunks = (e + 7) >> 3;
    for (int t = 0; t < nchunks; ++t) gather8(rcv, t, z, sub, a);
    float w = 1.0f / ((float)e + EPS_);   // dinv^2
    znxt[(row << 3) + sub] = pack_fp8x16v(a, w);
}

__global__ void spmm_L1(const int* __restrict__ cnt, const int* __restrict__ colell,
                        const uint4* __restrict__ z, uint4* __restrict__ znxt) {
    spmm_body(cnt, colell, z, znxt);
}
__global__ void spmm_L2(const int* __restrict__ cnt, const int* __restrict__ colell,
                        const uint4* __restrict__ z, uint4* __restrict__ znxt) {
    spmm_body(cnt, colell, z, znxt);
}

// ---- fused BPR loss: 2 elements per wave; u/p/n rows in 8-lane subgroups
__global__ void bpr_loss(const float4* __restrict__ ue, const float4* __restrict__ ie,
                         const uint4* __restrict__ z1, const uint4* __restrict__ z2,
                         const int* __restrict__ cnt, const int* __restrict__ colell,
                         const int* __restrict__ user, const int* __restrict__ pos,
                         const int* __restrict__ neg,
                         float* __restrict__ lacc, int* __restrict__ done,
                         float* __restrict__ out) {
    __shared__ float s[8];
    int wave = (blockIdx.x * 256 + threadIdx.x) >> 6;   // global wave id
    int lane = threadIdx.x & 63;
    int sg   = lane >> 3;          // 0..7
    int sub  = lane & 7;
    int half = sg >> 2;            // 0 = elem A, 1 = elem B
    int sgl  = sg & 3;             // 0=u 1=p 2=n 3=idle
    int el   = wave * 2 + half;
    int u = user[el];
    int p = N_USERS + pos[el] - 1;  // 1-indexed items
    int n = N_USERS + neg[el] - 1;
    int node = (sgl == 1) ? p : (sgl == 2) ? n : u;
    float cnode = 0.0f;
    vf2 vals[8];
    #pragma unroll
    for (int k = 0; k < 8; ++k) vals[k] = (vf2)(0.0f);
    if (sgl < 3) {
        int e = cnt[node];
        cnode = (float)e;
        // layer-0 exact from f32 embeddings: 4 float4 per lane
        const float4* eb = (node < N_USERS) ? ue : ie;
        int b4 = ((node < N_USERS) ? node : node - N_USERS) * 32 + sub * 4;
        float4 e0 = eb[b4], e1 = eb[b4 + 1], e2 = eb[b4 + 2], e3 = eb[b4 + 3];
        float w0 = rsqrtf(cnode + EPS_) * ZSCALE;
        vals[0] = (vf2){w0 * e0.x, w0 * e0.y}; vals[1] = (vf2){w0 * e0.z, w0 * e0.w};
        vals[2] = (vf2){w0 * e1.x, w0 * e1.y}; vals[3] = (vf2){w0 * e1.z, w0 * e1.w};
        vals[4] = (vf2){w0 * e2.x, w0 * e2.y}; vals[5] = (vf2){w0 * e2.z, w0 * e2.w};
        vals[6] = (vf2){w0 * e3.x, w0 * e3.y}; vals[7] = (vf2){w0 * e3.z, w0 * e3.w};
        int o = (node << 3) + sub;
        add_fp8x16v(vals, z1[o]);
        add_fp8x16v(vals, z2[o]);
        // inline layer-3 gather from z2 (f32), 8-edge padded chunks
        const int4* rcv = (const int4*)(colell + (node << 6));
        vf2 a[8];
        #pragma unroll
        for (int k = 0; k < 8; ++k) a[k] = (vf2)(0.0f);
        int nchunks = (e + 7) >> 3;
        for (int t = 0; t < nchunks; ++t) gather8(rcv, t, z2, sub, a);
        float w2 = 1.0f / (cnode + EPS_);   // dinv^2
        #pragma unroll
        for (int k = 0; k < 8; ++k) vals[k] += w2 * a[k];
    }
    // pull the u-subgroup (sg0 / sg4) values into all subgroups of the half
    int usrc = sub | (lane & 32);
    float dotp = 0.0f;
    #pragma unroll
    for (int k = 0; k < 8; ++k) {
        dotp += __shfl(vals[k].x, usrc) * vals[k].x;
        dotp += __shfl(vals[k].y, usrc) * vals[k].y;
    }
    dotp += __shfl_down(dotp, 4, 8);
    dotp += __shfl_down(dotp, 2, 8);
    dotp += __shfl_down(dotp, 1, 8);
    // subgroup heads now hold: lane (lane&32)+8 -> u.p, +16 -> u.n
    float sp = __shfl(dotp, (lane & 32) + 8);
    float sn = __shfl(dotp, (lane & 32) + 16);
    float cu = __shfl(cnode, (lane & 32) + 0);
    float cp = __shfl(cnode, (lane & 32) + 8);
    float cn = __shfl(cnode, (lane & 32) + 16);
    if ((lane & 31) == 0) {   // lane 0 (elem A) and lane 32 (elem B)
        float du = rsqrtf(cu + EPS_), dp = rsqrtf(cp + EPS_), dn = rsqrtf(cn + EPS_);
        const float inv = 1.0f / (16.0f * ZSCALE * ZSCALE);
        float diff = (sp / (du * dp) - sn / (du * dn)) * inv;
        // log_sigmoid(x) = min(x,0) - log1p(exp(-|x|))
        s[(threadIdx.x >> 6) * 2 + half] =
            fminf(diff, 0.0f) - log1pf(expf(-fabsf(diff)));
    }
    __syncthreads();
    if (threadIdx.x == 0) {
        float t = s[0] + s[1] + s[2] + s[3] + s[4] + s[5] + s[6] + s[7];
        atomicAdd(lacc, t);
        __threadfence();
        int prev = atomicAdd(done, 1);
        if (prev == BPR_BLOCKS - 1) {
            float total = atomicAdd(lacc, 0.0f);   // coherent read
            out[0] = -total * (1.0f / (float)BATCH);
        }
    }
}

extern "C" void kernel_launch(void* const* d_in, const int* in_sizes, int n_in,
                              void* d_out, int out_size, void* d_ws, size_t ws_size,
                              hipStream_t stream) {
    const float* ue  = (const float*)d_in[0];
    const float* ie  = (const float*)d_in[1];
    const int*   au  = (const int*)d_in[2];
    const int*   ai  = (const int*)d_in[3];
    const int*   usr = (const int*)d_in[4];
    const int*   pos = (const int*)d_in[5];
    const int*   neg = (const int*)d_in[6];
    float*       out = (float*)d_out;

    const size_t ZQ4 = (size_t)(NNODES + 1) * 8;  // uint4 per z buffer (+zero row)

    // ws layout (16B-aligned chunks):
    // z0 | z1 | z2 | fillc | fillc2 | fillc3 | [lacc done pad] | colell | colell2
    uint4* z0      = (uint4*)d_ws;
    uint4* z1      = z0 + ZQ4;
    uint4* z2      = z1 + ZQ4;
    int*   fillc   = (int*)(z2 + ZQ4);
    int*   fillc2  = fillc + NNODES;              // scratch for replica A
    int*   fillc3  = fillc2 + NNODES;             // scratch for replica B
    float* lacc    = (float*)(fillc3 + NNODES);
    int*   done    = (int*)(lacc + 1);
    int*   colell  = (int*)(lacc + 4);            // NNODES * STRIDE ints
    int*   colell2 = colell + (size_t)NNODES * STRIDE;  // scratch scatter target

    // fillc + fillc2 + fillc3 + lacc + done zeroed in one shot (~720 KB)
    hipMemsetAsync(fillc, 0, (3 * NNODES + 4) * sizeof(int), stream);

    // MEASUREMENT: two byte-identical scratch replicas of fill, then the
    // real fill. dur = 162.6 + 2*(F_warm + boundary). If F > 43us the
    // replicas appear in the rocprof top-5 with full counters.
    fill_ell<<<FILL_BLOCKS, 256, 0, stream>>>((const int4*)au, (const int4*)ai,
                                              fillc2, colell2);
    fill_ell<<<FILL_BLOCKS, 256, 0, stream>>>((const int4*)au, (const int4*)ai,
                                              fillc3, colell2);
    fill_ell<<<FILL_BLOCKS, 256, 0, stream>>>((const int4*)au, (const int4*)ai,
                                              fillc, colell);
    init_z<<<INIT_BLOCKS, 256, 0, stream>>>(fillc, (const float4*)ue,
                                            (const float4*)ie, (uint2*)z0,
                                            (uint2*)z1, (uint2*)z2, colell);

    spmm_L1<<<FULL_BLOCKS, 256, 0, stream>>>(fillc, colell, z0, z1);
    spmm_L2<<<FULL_BLOCKS, 256, 0, stream>>>(fillc, colell, z1, z2);

    bpr_loss<<<BPR_BLOCKS, 256, 0, stream>>>((const float4*)ue, (const float4*)ie,
                                             z1, z2, fillc, colell,
                                             usr, pos, neg, lacc, done, out);
}

// Round 12
// 169.757 us; speedup vs baseline: 3.0843x; 1.3304x over previous
//
#include <hip/hip_runtime.h>
#include <math.h>

#define N_USERS 40000
#define N_ITEMS 20000
#define NNODES  60000          // N_USERS + N_ITEMS; also the zero-pad row index
#define D       128
#define N_EDGES 320000
#define EPS_    1e-7f
#define BATCH   4096
#define STRIDE  64             // ELL row capacity (max degree ~45 for Poisson(16))
#define ZSCALE  256.0f         // fp8 storage scale; folded out in bpr
#define BPR_BLOCKS (BATCH / 8)             // 512: 4 waves x 2 elements each
#define FILL_GRPS  320                     // blocks per bucket
#define FILL_BLOCKS (8 * FILL_GRPS)        // 2560
#define WARM_BLOCKS 512                    // prefetch/zero-row blocks appended to fill
#define U4   (N_USERS * 32)                // float4 count of ue
#define TOT4 ((N_USERS + N_ITEMS) * 32)    // float4 count of ue+ie
#define INIT_BLOCKS (NNODES * 16 / 256)    // 3750 (16 thr/row)
#define FULL_BLOCKS (NNODES * 8 / 256)     // 1875 (8 threads per row)

// MEASURED BUDGET (R9-R11): fill ~27us (L2-transaction-bound: 1.28M scattered
// 4B atomic+write through 8 XCD-L2s), spmm 9.35us x2 (VALU-bound 68%, fp8
// unpack), init/bpr < 2.7us warm, boundary ~4.2us, ~85us cold effects from
// the 268MB workspace poison evicting L2/L3 (inputs included) pre-launch.
// THIS ROUND: (1) 512 warm-up blocks ride the fill dispatch — prefetch
// ue/ie (30MB) into L3 under fill's L2-bound shadow, write z zero-rows,
// zero lacc/done (memset shrinks to fillc only); (2) rows pad to 4 (not 8)
// + gather4 tail cuts ~half the padded-edge VALU in spmm/bpr; (3) colell
// stores node<<3 to shave a shift per gather.

typedef float vf2 __attribute__((ext_vector_type(2)));

// unpack 16 fp8 (e4m3) from uint4, accumulate into 8 packed-f32 pairs.
__device__ __forceinline__ void add_fp8x16v(vf2* a, uint4 t) {
    a[0] += __builtin_amdgcn_cvt_pk_f32_fp8(t.x, false);
    a[1] += __builtin_amdgcn_cvt_pk_f32_fp8(t.x, true);
    a[2] += __builtin_amdgcn_cvt_pk_f32_fp8(t.y, false);
    a[3] += __builtin_amdgcn_cvt_pk_f32_fp8(t.y, true);
    a[4] += __builtin_amdgcn_cvt_pk_f32_fp8(t.z, false);
    a[5] += __builtin_amdgcn_cvt_pk_f32_fp8(t.z, true);
    a[6] += __builtin_amdgcn_cvt_pk_f32_fp8(t.w, false);
    a[7] += __builtin_amdgcn_cvt_pk_f32_fp8(t.w, true);
}

// scale + clamp + pack 8 vf2 (16 f32) -> 16 fp8 (e4m3) in uint4
__device__ __forceinline__ uint4 pack_fp8x16v(const vf2* a, float w) {
    float v[16];
    #pragma unroll
    for (int k = 0; k < 8; ++k) {
        v[2 * k]     = fminf(fmaxf(w * a[k].x, -448.0f), 448.0f);
        v[2 * k + 1] = fminf(fmaxf(w * a[k].y, -448.0f), 448.0f);
    }
    int w0 = __builtin_amdgcn_cvt_pk_fp8_f32(v[0],  v[1],  0,  false);
    w0     = __builtin_amdgcn_cvt_pk_fp8_f32(v[2],  v[3],  w0, true);
    int w1 = __builtin_amdgcn_cvt_pk_fp8_f32(v[4],  v[5],  0,  false);
    w1     = __builtin_amdgcn_cvt_pk_fp8_f32(v[6],  v[7],  w1, true);
    int w2 = __builtin_amdgcn_cvt_pk_fp8_f32(v[8],  v[9],  0,  false);
    w2     = __builtin_amdgcn_cvt_pk_fp8_f32(v[10], v[11], w2, true);
    int w3 = __builtin_amdgcn_cvt_pk_fp8_f32(v[12], v[13], 0,  false);
    w3     = __builtin_amdgcn_cvt_pk_fp8_f32(v[14], v[15], w3, true);
    uint4 o; o.x = (unsigned)w0; o.y = (unsigned)w1;
    o.z = (unsigned)w2; o.w = (unsigned)w3;
    return o;
}

// gather 8 padded edges (cols pre-scaled by 8; 2 int4 col loads)
__device__ __forceinline__ void gather8(const int4* __restrict__ rcv, int t,
                                        const uint4* __restrict__ z, int sub,
                                        vf2* a) {
    int4 ca = rcv[2 * t], cb = rcv[2 * t + 1];
    uint4 t0 = z[ca.x + sub];
    uint4 t1 = z[ca.y + sub];
    uint4 t2 = z[ca.z + sub];
    uint4 t3 = z[ca.w + sub];
    uint4 t4 = z[cb.x + sub];
    uint4 t5 = z[cb.y + sub];
    uint4 t6 = z[cb.z + sub];
    uint4 t7 = z[cb.w + sub];
    add_fp8x16v(a, t0); add_fp8x16v(a, t1);
    add_fp8x16v(a, t2); add_fp8x16v(a, t3);
    add_fp8x16v(a, t4); add_fp8x16v(a, t5);
    add_fp8x16v(a, t6); add_fp8x16v(a, t7);
}

// gather 4 padded edges (tail chunk; 1 int4 col load)
__device__ __forceinline__ void gather4(const int4* __restrict__ rcv, int t4,
                                        const uint4* __restrict__ z, int sub,
                                        vf2* a) {
    int4 ca = rcv[t4];
    uint4 t0 = z[ca.x + sub];
    uint4 t1 = z[ca.y + sub];
    uint4 t2 = z[ca.z + sub];
    uint4 t3 = z[ca.w + sub];
    add_fp8x16v(a, t0); add_fp8x16v(a, t1);
    add_fp8x16v(a, t2); add_fp8x16v(a, t3);
}

// shared padded-gather loop: rows padded to multiple of 4; bulk 8s + one 4
__device__ __forceinline__ void gather_row(const int4* __restrict__ rcv, int e,
                                           const uint4* __restrict__ z, int sub,
                                           vf2* a) {
    int n4 = (e + 3) >> 2;            // 4-edge groups (padded)
    int nf = n4 >> 1;                 // full 8-edge chunks
    for (int t = 0; t < nf; ++t) gather8(rcv, t, z, sub, a);
    if (n4 & 1) gather4(rcv, n4 - 1, z, sub, a);
}

// ---- bucketed ELL fill + warm-up blocks ----------------------------------
// blocks [0, FILL_BLOCKS): bucketed scatter (users: u/10000, items: 4+i/5000;
// blockIdx&7 -> XCD-local L2 writes, R11 prior session: -30us vs naive).
// blocks [FILL_BLOCKS, +WARM_BLOCKS): stream-prefetch ue/ie back into L3
// (poison evicted them), write z zero-rows, zero lacc/done.
__global__ void fill_ell(const int4* __restrict__ au4, const int4* __restrict__ ai4,
                         int* __restrict__ fillc, int* __restrict__ colell,
                         const float4* __restrict__ ue, const float4* __restrict__ ie,
                         uint2* __restrict__ z0, uint2* __restrict__ z1,
                         uint2* __restrict__ z2, float* __restrict__ lacc,
                         int* __restrict__ done) {
    if (blockIdx.x >= FILL_BLOCKS) {
        int t = (blockIdx.x - FILL_BLOCKS) * 256 + threadIdx.x;
        if (t < 16)       z0[NNODES * 16 + t] = make_uint2(0u, 0u);
        else if (t < 32)  z1[NNODES * 16 + (t - 16)] = make_uint2(0u, 0u);
        else if (t < 48)  z2[NNODES * 16 + (t - 32)] = make_uint2(0u, 0u);
        else if (t == 48) *lacc = 0.0f;
        else if (t == 49) *done = 0;
        float acc = 0.0f;
        for (int i = t; i < TOT4; i += WARM_BLOCKS * 256) {
            float4 v = (i < U4) ? ue[i] : ie[i - U4];
            acc += v.x + v.y + v.z + v.w;
        }
        asm volatile("" :: "v"(acc));   // keep the prefetch alive (rule #17)
        return;
    }
    const int bucket = blockIdx.x & 7;
    const int grp    = blockIdx.x >> 3;          // 0..FILL_GRPS-1
    const int NE4    = N_EDGES / 4;
    for (int i = grp * 256 + threadIdx.x; i < NE4; i += FILL_GRPS * 256) {
        int4 us = au4[i];
        int4 is = ai4[i];
        int ua[4] = { us.x, us.y, us.z, us.w };
        int ia[4] = { is.x, is.y, is.z, is.w };
        #pragma unroll
        for (int k = 0; k < 4; ++k) {
            int u    = ua[k];
            int iraw = ia[k];
            int it   = N_USERS + iraw;
            if (u / 10000 == bucket) {
                int p = atomicAdd(&fillc[u], 1);
                if (p < STRIDE) colell[(u << 6) + p] = it << 3;   // pre-scaled
            }
            if (4 + iraw / 5000 == bucket) {
                int p = atomicAdd(&fillc[it], 1);
                if (p < STRIDE) colell[(it << 6) + p] = u << 3;   // pre-scaled
            }
        }
    }
}

// ---- z0 init + colell 4-padding ------------------------------------------
// 16 threads per row. Zero-rows/lacc/done already handled by fill warm-up.
__global__ void init_z(const int* __restrict__ fillc,
                       const float4* __restrict__ ue, const float4* __restrict__ ie,
                       uint2* __restrict__ z0, int* __restrict__ colell) {
    int i   = blockIdx.x * 256 + threadIdx.x;
    int row = i >> 4;
    int sub = i & 15;
    int e = fillc[row];
    if (sub == 0) {                      // pad colell row to a multiple of 4
        int ep = (e + 3) & ~3;
        for (int k = e; k < ep; ++k) colell[(row << 6) + k] = NNODES << 3;
    }
    float w = rsqrtf((float)e + EPS_) * ZSCALE;
    float4 e0, e1;
    if (row < N_USERS) {
        int b4 = row * 32 + sub * 2;     // 32 float4 per row
        e0 = ue[b4]; e1 = ue[b4 + 1];
    } else {
        int b4 = (row - N_USERS) * 32 + sub * 2;
        e0 = ie[b4]; e1 = ie[b4 + 1];
    }
    float v[8] = { e0.x * w, e0.y * w, e0.z * w, e0.w * w,
                   e1.x * w, e1.y * w, e1.z * w, e1.w * w };
    float c[8];
    #pragma unroll
    for (int k = 0; k < 8; ++k) c[k] = fminf(fmaxf(v[k], -448.0f), 448.0f);
    int lo = __builtin_amdgcn_cvt_pk_fp8_f32(c[0], c[1], 0,  false);
    lo     = __builtin_amdgcn_cvt_pk_fp8_f32(c[2], c[3], lo, true);
    int hi = __builtin_amdgcn_cvt_pk_fp8_f32(c[4], c[5], 0,  false);
    hi     = __builtin_amdgcn_cvt_pk_fp8_f32(c[6], c[7], hi, true);
    z0[i] = make_uint2((unsigned)lo, (unsigned)hi);
}

// ---- SpMM, 8-lane subgroup rows, 4-padded chunks (mixed rows) ------------
__device__ __forceinline__ void spmm_body(const int* __restrict__ cnt,
                                          const int* __restrict__ colell,
                                          const uint4* __restrict__ z,
                                          uint4* __restrict__ znxt) {
    int tid = blockIdx.x * 256 + threadIdx.x;
    int row = tid >> 3;               // 32 rows per 256-thread block
    int sub = threadIdx.x & 7;
    int e = cnt[row];
    const int4* rcv = (const int4*)(colell + (row << 6));
    vf2 a[8];
    #pragma unroll
    for (int k = 0; k < 8; ++k) a[k] = (vf2)(0.0f);
    gather_row(rcv, e, z, sub, a);
    float w = 1.0f / ((float)e + EPS_);   // dinv^2
    znxt[(row << 3) + sub] = pack_fp8x16v(a, w);
}

__global__ void spmm_L1(const int* __restrict__ cnt, const int* __restrict__ colell,
                        const uint4* __restrict__ z, uint4* __restrict__ znxt) {
    spmm_body(cnt, colell, z, znxt);
}
__global__ void spmm_L2(const int* __restrict__ cnt, const int* __restrict__ colell,
                        const uint4* __restrict__ z, uint4* __restrict__ znxt) {
    spmm_body(cnt, colell, z, znxt);
}

// ---- fused BPR loss: 2 elements per wave; u/p/n rows in 8-lane subgroups
__global__ void bpr_loss(const float4* __restrict__ ue, const float4* __restrict__ ie,
                         const uint4* __restrict__ z1, const uint4* __restrict__ z2,
                         const int* __restrict__ cnt, const int* __restrict__ colell,
                         const int* __restrict__ user, const int* __restrict__ pos,
                         const int* __restrict__ neg,
                         float* __restrict__ lacc, int* __restrict__ done,
                         float* __restrict__ out) {
    __shared__ float s[8];
    int wave = (blockIdx.x * 256 + threadIdx.x) >> 6;   // global wave id
    int lane = threadIdx.x & 63;
    int sg   = lane >> 3;          // 0..7
    int sub  = lane & 7;
    int half = sg >> 2;            // 0 = elem A, 1 = elem B
    int sgl  = sg & 3;             // 0=u 1=p 2=n 3=idle
    int el   = wave * 2 + half;
    int u = user[el];
    int p = N_USERS + pos[el] - 1;  // 1-indexed items
    int n = N_USERS + neg[el] - 1;
    int node = (sgl == 1) ? p : (sgl == 2) ? n : u;
    float cnode = 0.0f;
    vf2 vals[8];
    #pragma unroll
    for (int k = 0; k < 8; ++k) vals[k] = (vf2)(0.0f);
    if (sgl < 3) {
        int e = cnt[node];
        cnode = (float)e;
        // layer-0 exact from f32 embeddings: 4 float4 per lane
        const float4* eb = (node < N_USERS) ? ue : ie;
        int b4 = ((node < N_USERS) ? node : node - N_USERS) * 32 + sub * 4;
        float4 e0 = eb[b4], e1 = eb[b4 + 1], e2 = eb[b4 + 2], e3 = eb[b4 + 3];
        float w0 = rsqrtf(cnode + EPS_) * ZSCALE;
        vals[0] = (vf2){w0 * e0.x, w0 * e0.y}; vals[1] = (vf2){w0 * e0.z, w0 * e0.w};
        vals[2] = (vf2){w0 * e1.x, w0 * e1.y}; vals[3] = (vf2){w0 * e1.z, w0 * e1.w};
        vals[4] = (vf2){w0 * e2.x, w0 * e2.y}; vals[5] = (vf2){w0 * e2.z, w0 * e2.w};
        vals[6] = (vf2){w0 * e3.x, w0 * e3.y}; vals[7] = (vf2){w0 * e3.z, w0 * e3.w};
        int o = (node << 3) + sub;
        add_fp8x16v(vals, z1[o]);
        add_fp8x16v(vals, z2[o]);
        // inline layer-3 gather from z2 (f32), 4-padded chunks
        const int4* rcv = (const int4*)(colell + (node << 6));
        vf2 a[8];
        #pragma unroll
        for (int k = 0; k < 8; ++k) a[k] = (vf2)(0.0f);
        gather_row(rcv, e, z2, sub, a);
        float w2 = 1.0f / (cnode + EPS_);   // dinv^2
        #pragma unroll
        for (int k = 0; k < 8; ++k) vals[k] += w2 * a[k];
    }
    // pull the u-subgroup (sg0 / sg4) values into all subgroups of the half
    int usrc = sub | (lane & 32);
    float dotp = 0.0f;
    #pragma unroll
    for (int k = 0; k < 8; ++k) {
        dotp += __shfl(vals[k].x, usrc) * vals[k].x;
        dotp += __shfl(vals[k].y, usrc) * vals[k].y;
    }
    dotp += __shfl_down(dotp, 4, 8);
    dotp += __shfl_down(dotp, 2, 8);
    dotp += __shfl_down(dotp, 1, 8);
    // subgroup heads now hold: lane (lane&32)+8 -> u.p, +16 -> u.n
    float sp = __shfl(dotp, (lane & 32) + 8);
    float sn = __shfl(dotp, (lane & 32) + 16);
    float cu = __shfl(cnode, (lane & 32) + 0);
    float cp = __shfl(cnode, (lane & 32) + 8);
    float cn = __shfl(cnode, (lane & 32) + 16);
    if ((lane & 31) == 0) {   // lane 0 (elem A) and lane 32 (elem B)
        float du = rsqrtf(cu + EPS_), dp = rsqrtf(cp + EPS_), dn = rsqrtf(cn + EPS_);
        const float inv = 1.0f / (16.0f * ZSCALE * ZSCALE);
        float diff = (sp / (du * dp) - sn / (du * dn)) * inv;
        // log_sigmoid(x) = min(x,0) - log1p(exp(-|x|))
        s[(threadIdx.x >> 6) * 2 + half] =
            fminf(diff, 0.0f) - log1pf(expf(-fabsf(diff)));
    }
    __syncthreads();
    if (threadIdx.x == 0) {
        float t = s[0] + s[1] + s[2] + s[3] + s[4] + s[5] + s[6] + s[7];
        atomicAdd(lacc, t);
        __threadfence();
        int prev = atomicAdd(done, 1);
        if (prev == BPR_BLOCKS - 1) {
            float total = atomicAdd(lacc, 0.0f);   // coherent read
            out[0] = -total * (1.0f / (float)BATCH);
        }
    }
}

extern "C" void kernel_launch(void* const* d_in, const int* in_sizes, int n_in,
                              void* d_out, int out_size, void* d_ws, size_t ws_size,
                              hipStream_t stream) {
    const float* ue  = (const float*)d_in[0];
    const float* ie  = (const float*)d_in[1];
    const int*   au  = (const int*)d_in[2];
    const int*   ai  = (const int*)d_in[3];
    const int*   usr = (const int*)d_in[4];
    const int*   pos = (const int*)d_in[5];
    const int*   neg = (const int*)d_in[6];
    float*       out = (float*)d_out;

    const size_t ZQ4 = (size_t)(NNODES + 1) * 8;  // uint4 per z buffer (+zero row)

    // ws layout (16B-aligned chunks):
    // z0 | z1 | z2 (fp8, NNODES+1 rows) | [fillc | lacc | done | pad] | colell
    uint4* z0     = (uint4*)d_ws;
    uint4* z1     = z0 + ZQ4;
    uint4* z2     = z1 + ZQ4;
    int*   fillc  = (int*)(z2 + ZQ4);
    float* lacc   = (float*)(fillc + NNODES);
    int*   done   = (int*)(lacc + 1);
    int*   colell = (int*)(lacc + 4);             // NNODES * STRIDE ints

    // only fillc needs the memset now (lacc/done zeroed by fill warm-up)
    hipMemsetAsync(fillc, 0, NNODES * sizeof(int), stream);

    fill_ell<<<FILL_BLOCKS + WARM_BLOCKS, 256, 0, stream>>>(
        (const int4*)au, (const int4*)ai, fillc, colell,
        (const float4*)ue, (const float4*)ie,
        (uint2*)z0, (uint2*)z1, (uint2*)z2, lacc, done);
    init_z<<<INIT_BLOCKS, 256, 0, stream>>>(fillc, (const float4*)ue,
                                            (const float4*)ie, (uint2*)z0, colell);

    spmm_L1<<<FULL_BLOCKS, 256, 0, stream>>>(fillc, colell, z0, z1);
    spmm_L2<<<FULL_BLOCKS, 256, 0, stream>>>(fillc, colell, z1, z2);

    bpr_loss<<<BPR_BLOCKS, 256, 0, stream>>>((const float4*)ue, (const float4*)ie,
                                             z1, z2, fillc, colell,
                                             usr, pos, neg, lacc, done, out);
}